// Round 6
// baseline (239.851 us; speedup 1.0000x reference)
//
#include <hip/hip_runtime.h>
#include <stdint.h>

// S6Layer on MI355X. B=8, L=4096, DM=256, DI=384, DS=8, CHUNK=32.
// R10, driven by R4 counters (GEMM1 61us, MfmaUtil 12.5%, VALUBusy 31%,
// hbm 27%, occ 36%, VGPR=48):
//  1. A-fragment REGISTER PREFETCH, window PF=8 (64 VGPRs), issued BEFORE the
//     B-stage __syncthreads: the barrier's vmcnt(0) drain absorbs the load
//     latency we were paying per-kt (VGPR=48 proved the compiler kept ~1 load
//     in flight; each kt stalled ~200cy L2 latency vs 39cy of MFMA).
//     sched_barrier(0) pins the prefetch against sinking (R2-R4 lesson).
//     K=256: K-loop is pure ds_read+MFMA. K=384: chunks 8..11 issued 8 iters
//     (~500cy) ahead. Register WAR on the af window is HW-scoreboard-safe.
//  2. silu: IEEE divide -> x * v_rcp_f32 (1 ulp f32, invisible at bf16).
// R11: resubmission of R10 verbatim — bench died on container acquisition
// ("MI355X container failed twice"), zero signal received.
// R9: A direct global->VGPR (frag = 16 contiguous B), B swizzle folded to 2
// per-lane bases + immediates, softplus via __logf(1+__expf).
// Epilogue LDS staging pad 72 (~2-way, 575 cy/block at R4 counters - done).
#define B_  8
#define L_  4096
#define DM  256
#define DI  384
#define DS  8
#define M_  (B_*L_)   // 32768 tokens

typedef float f32x4 __attribute__((ext_vector_type(4)));
typedef short s16x8 __attribute__((ext_vector_type(8)));

#define AS1(p) ((__attribute__((address_space(1))) void*)(p))
#define AS3(p) ((__attribute__((address_space(3))) void*)(p))

__device__ __forceinline__ unsigned short f2bf(float f) {
  union { float f; uint32_t u; } v; v.f = f;
  uint32_t r = v.u + 0x7FFFu + ((v.u >> 16) & 1u);   // RNE
  return (unsigned short)(r >> 16);
}
__device__ __forceinline__ float bf2f(unsigned short h) {
  union { uint32_t u; float f; } v; v.u = ((uint32_t)h) << 16;
  return v.f;
}
__device__ __forceinline__ float silu_f(float x) {
  return x * __builtin_amdgcn_rcpf(1.f + __expf(-x));
}

// ---------------- weight fp32 -> bf16 ----------------
__global__ __launch_bounds__(256) void cvt_kernel(
    const float* __restrict__ w0, const float* __restrict__ w1, const float* __restrict__ w2,
    unsigned short* __restrict__ o0, unsigned short* __restrict__ o1, unsigned short* __restrict__ o2) {
  int i = blockIdx.x * 256 + threadIdx.x;
  if (i < 3*DI*DM) o0[i] = f2bf(w0[i]);
  if (i < DI*DI)   o1[i] = f2bf(w1[i]);
  if (i < DM*DI)   o2[i] = f2bf(w2[i]);
}

// ---------------- layernorm: one wave per token ----------------
__global__ __launch_bounds__(256) void ln_kernel(
    const float* __restrict__ x, const float* __restrict__ gamma, const float* __restrict__ beta,
    unsigned short* __restrict__ xn) {
  int token = blockIdx.x * 4 + (threadIdx.x >> 6);
  int lane  = threadIdx.x & 63;
  const float4 v = *(const float4*)(x + (size_t)token*DM + lane*4);
  float s  = v.x + v.y + v.z + v.w;
  float ss = v.x*v.x + v.y*v.y + v.z*v.z + v.w*v.w;
  #pragma unroll
  for (int off = 32; off > 0; off >>= 1) {
    s  += __shfl_xor(s,  off, 64);
    ss += __shfl_xor(ss, off, 64);
  }
  float mean = s * (1.f/DM);
  float var  = ss * (1.f/DM) - mean*mean;
  float rstd = rsqrtf(var + 1e-5f);
  const float4 g = *(const float4*)(gamma + lane*4);
  const float4 b = *(const float4*)(beta  + lane*4);
  ushort4 o;
  o.x = f2bf((v.x - mean)*rstd*g.x + b.x);
  o.y = f2bf((v.y - mean)*rstd*g.y + b.y);
  o.z = f2bf((v.z - mean)*rstd*g.z + b.z);
  o.w = f2bf((v.w - mean)*rstd*g.w + b.w);
  *(ushort4*)(xn + (size_t)token*DM + lane*4) = o;
}

// ---------------- weights-stationary MFMA GEMM, A reg-prefetch -------------
// C[M,N] = A[M,K] @ Bw[N,K]^T. Block: 256 thr (4 waves), tile 128M x 64N;
// wave w owns rows w*32..w*32+31 (2 mi tiles) x all 64 N (4 ni tiles).
// LDS: B panel only, 64 x K bf16, staged once via global_load_lds with the
// 16B-chunk XOR swizzle: LDS[row][j] = G[row][(j&~7)|((j&7)^(row&7))].
// A frags prefetched to a PF=8-deep register window before the barrier;
// K-loop per kt: (K=384 only: 2 refill loads, 8 iters ahead) + 4
// ds_read_b128 (imm offsets off 2 per-lane bases) + 8 MFMA.
template<int EPI, int KSTEPS>
__global__ __launch_bounds__(256, 3) void gemm_ws(
    const unsigned short* __restrict__ A,   // [M,K] bf16
    const unsigned short* __restrict__ Bw,  // [N,K] bf16
    const float* __restrict__ bias,         // [N]
    unsigned short* __restrict__ o_xp, unsigned short* __restrict__ o_z,
    unsigned short* __restrict__ o_dtin,    // EPI=1
    unsigned short* __restrict__ o_bf,      // EPI=2
    const float* __restrict__ resid, float* __restrict__ o_f)  // EPI=3
{
  constexpr int K    = KSTEPS * 32;
  constexpr int CPR  = K / 8;               // 16B chunks per B row
  constexpr int PF   = (KSTEPS < 8) ? KSTEPS : 8;   // A prefetch window
  __shared__ unsigned short smem[64*K];     // 48KB (K=384) / 32KB (K=256)
  unsigned short* sB = smem;

  const int t    = threadIdx.x;
  const int lane = t & 63;
  const int w    = t >> 6;
  const int fr   = lane & 15;
  const int fq   = lane >> 4;
  const int mbase = blockIdx.x * 128;
  const int nbase = blockIdx.y * 64;
  const int wm   = w * 32;

  // ---- stage B panel (once): LDS slot c holds swizzled global chunk ----
  #pragma unroll
  for (int i = 0; i < (64*CPR)/256; ++i) {
    int c   = i*256 + t;
    int row = c / CPR;
    int j   = c - row*CPR;
    int jp  = (j & ~7) | ((j & 7) ^ (row & 7));
    __builtin_amdgcn_global_load_lds(AS1(Bw + (size_t)(nbase + row)*K + jp*8),
                                     AS3(sB + c*8), 16, 0, 0);
  }

  // ---- A fragment base: af[mi][kt] = A[mbase+wm+mi*16+fr][kt*32+fq*8 ..+7]
  const unsigned short* gA0 = A + (size_t)(mbase + wm + fr)*K + fq*8;
  const unsigned short* gA1 = gA0 + (size_t)16*K;

  // ---- prefetch A window: all in flight before the barrier; the barrier's
  // vmcnt(0) drain (needed for the B panel anyway) absorbs their latency.
  s16x8 af[PF][2];
  #pragma unroll
  for (int p = 0; p < PF; ++p) {
    af[p][0] = *(const s16x8*)(gA0 + p*32);
    af[p][1] = *(const s16x8*)(gA1 + p*32);
  }
  __builtin_amdgcn_sched_barrier(0);   // pin: prefetch must not sink below

  // ---- B LDS read bases: byte addr for (ni,kt) decomposes as
  //   fr*2K + ((fq^(fr&7)) ^ 4*(kt&1))*16  +  ni*32K + (kt>>1)*128
  const unsigned short* sBrE = sB + (size_t)fr*K + ( fq      ^ (fr & 7))*8;
  const unsigned short* sBrO = sB + (size_t)fr*K + ((fq | 4) ^ (fr & 7))*8;

  f32x4 acc[2][4];
  #pragma unroll
  for (int mi = 0; mi < 2; ++mi)
    #pragma unroll
    for (int ni = 0; ni < 4; ++ni) acc[mi][ni] = (f32x4){0.f, 0.f, 0.f, 0.f};

  __syncthreads();   // B panel + A window resident

  #pragma unroll
  for (int kt = 0; kt < KSTEPS; ++kt) {
    s16x8 a0 = af[kt % PF][0];
    s16x8 a1 = af[kt % PF][1];
    if (kt + PF < KSTEPS) {          // K=384 only: refill 8 iters ahead
      af[kt % PF][0] = *(const s16x8*)(gA0 + (kt + PF)*32);
      af[kt % PF][1] = *(const s16x8*)(gA1 + (kt + PF)*32);
    }
    const unsigned short* bb = (kt & 1) ? sBrO : sBrE;
    s16x8 bfr[4];
    #pragma unroll
    for (int ni = 0; ni < 4; ++ni)
      bfr[ni] = *(const s16x8*)(bb + ni*16*K + (kt >> 1)*64);
    #pragma unroll
    for (int ni = 0; ni < 4; ++ni) {
      acc[0][ni] = __builtin_amdgcn_mfma_f32_16x16x32_bf16(a0, bfr[ni], acc[0][ni], 0, 0, 0);
      acc[1][ni] = __builtin_amdgcn_mfma_f32_16x16x32_bf16(a1, bfr[ni], acc[1][ni], 0, 0, 0);
    }
  }

  // ---- epilogue: C layout per 16x16 tile: col=fr, row=fq*4+r (m89) ----
  if constexpr (EPI == 3) {
    #pragma unroll
    for (int ni = 0; ni < 4; ++ni) {
      int gn = nbase + ni*16 + fr;
      float bv = bias[gn];
      #pragma unroll
      for (int mi = 0; mi < 2; ++mi) {
        int gm0 = mbase + wm + mi*16 + fq*4;
        #pragma unroll
        for (int r = 0; r < 4; ++r) {
          size_t gm = (size_t)(gm0 + r);
          o_f[gm*DM + gn] = acc[mi][ni][r] + bv + resid[gm*DM + gn];
        }
      }
    }
  } else {
    __syncthreads();   // all waves done with sB -> reuse for C staging
    const bool do_silu = (EPI == 1) && (blockIdx.y < 12);   // panels 0-5 xp, 6-11 z
    // stage with pad-72 row stride (144B == 4 mod 32 banks -> ~2-way on writes)
    #pragma unroll
    for (int ni = 0; ni < 4; ++ni) {
      int cn = ni*16 + fr;
      float bv = bias[nbase + cn];
      #pragma unroll
      for (int mi = 0; mi < 2; ++mi) {
        int rm0 = wm + mi*16 + fq*4;
        #pragma unroll
        for (int r = 0; r < 4; ++r) {
          float c = acc[mi][ni][r] + bv;
          if constexpr (EPI == 1) { if (do_silu) c = silu_f(c); }
          else                    { c = (c > 20.f) ? c : __logf(1.f + __expf(c)); }
          smem[(rm0 + r)*72 + cn] = f2bf(c);
        }
      }
    }
    __syncthreads();
    unsigned short* dst;
    int colbase;
    if constexpr (EPI == 1) {
      int p = blockIdx.y;                       // 0..17
      dst = (p < 6) ? o_xp : (p < 12) ? o_z : o_dtin;
      colbase = (p % 6) * 64;
    } else {
      dst = o_bf; colbase = nbase;
    }
    const int rr = t >> 3, cc = (t & 7) * 8;
    #pragma unroll
    for (int it = 0; it < 4; ++it) {
      int row = rr + it*32;
      s16x8 v = *(const s16x8*)(smem + row*72 + cc);
      *(s16x8*)(dst + (size_t)(mbase + row)*DI + colbase + cc) = v;
    }
  }
}

// ---------------- chunked selective scan ----------------
__global__ __launch_bounds__(384) void scan_kernel(
    const unsigned short* __restrict__ xp, const unsigned short* __restrict__ dt,
    const unsigned short* __restrict__ zb, const float* __restrict__ A_log,
    const float* __restrict__ D_vec, unsigned short* __restrict__ yz) {
  int g  = blockIdx.x;
  int di = threadIdx.x;
  size_t base = (size_t)g * 32 * DI + di;
  float a[DS];
  #pragma unroll
  for (int s = 0; s < DS; ++s) a[s] = -__expf(A_log[di*DS + s]);
  float Dv = D_vec[di];
  float h[DS] = {0.f,0.f,0.f,0.f,0.f,0.f,0.f,0.f};
  for (int tt = 0; tt < 32; ++tt) {
    size_t idx = base + (size_t)tt * DI;
    float xv  = bf2f(xp[idx]);
    float dtv = bf2f(dt[idx]);
    float y = 0.f;
    #pragma unroll
    for (int s = 0; s < DS; ++s) {
      h[s] = h[s] * __expf(dtv * a[s]) + xv;
      y += h[s];
    }
    float zv = bf2f(zb[idx]);
    yz[idx] = f2bf(y * zv + xv * Dv);
  }
}

extern "C" void kernel_launch(void* const* d_in, const int* in_sizes, int n_in,
                              void* d_out, int out_size, void* d_ws, size_t ws_size,
                              hipStream_t stream) {
  const float* x     = (const float*)d_in[0];
  const float* gamma = (const float*)d_in[1];
  const float* beta  = (const float*)d_in[2];
  const float* W_in  = (const float*)d_in[3];
  const float* b_in  = (const float*)d_in[4];
  const float* W_dt  = (const float*)d_in[5];
  const float* b_dt  = (const float*)d_in[6];
  const float* A_log = (const float*)d_in[7];
  const float* D_vec = (const float*)d_in[8];
  const float* W_out = (const float*)d_in[9];
  const float* b_out = (const float*)d_in[10];
  float* out = (float*)d_out;

  char* ws = (char*)d_ws;
  size_t off = 0;
  auto alloc = [&](size_t bytes) -> char* {
    char* p = ws + off; off += (bytes + 255) & ~(size_t)255; return p;
  };
  unsigned short* xn    = (unsigned short*)alloc((size_t)M_*DM*2);
  unsigned short* xpb   = (unsigned short*)alloc((size_t)M_*DI*2);
  unsigned short* zb    = (unsigned short*)alloc((size_t)M_*DI*2);
  unsigned short* dtin  = (unsigned short*)alloc((size_t)M_*DI*2);
  unsigned short* dtb   = (unsigned short*)alloc((size_t)M_*DI*2);
  unsigned short* yzb   = dtin;   // dtin dead after GEMM2 -> reuse for yz
  unsigned short* winb  = (unsigned short*)alloc((size_t)3*DI*DM*2);
  unsigned short* wdtb  = (unsigned short*)alloc((size_t)DI*DI*2);
  unsigned short* woutb = (unsigned short*)alloc((size_t)DM*DI*2);

  cvt_kernel<<<dim3((3*DI*DM + 255)/256), 256, 0, stream>>>(W_in, W_dt, W_out, winb, wdtb, woutb);
  ln_kernel<<<dim3(M_/4), 256, 0, stream>>>(x, gamma, beta, xn);
  // GEMM1: xn[M,256] @ W_in[1152,256]^T -> silu(xp), silu(z), dtin
  gemm_ws<1, 8><<<dim3(M_/128, (3*DI)/64), 256, 0, stream>>>(
      xn, winb, b_in, xpb, zb, dtin, nullptr, nullptr, nullptr);
  // GEMM2: dtin[M,384] @ W_dt[384,384]^T ; softplus -> dt
  gemm_ws<2, 12><<<dim3(M_/128, DI/64), 256, 0, stream>>>(
      dtin, wdtb, b_dt, nullptr, nullptr, nullptr, dtb, nullptr, nullptr);
  // scan -> yz = y*z + xp*D
  scan_kernel<<<dim3(M_/32), DI, 0, stream>>>(xpb, dtb, zb, A_log, D_vec, yzb);
  // GEMM3: yz[M,384] @ W_out[256,384]^T + b_out + residual -> out (fp32)
  gemm_ws<3, 12><<<dim3(M_/128, DM/64), 256, 0, stream>>>(
      yzb, woutb, b_out, nullptr, nullptr, nullptr, nullptr, x, out);
}

// Round 7
// 224.186 us; speedup vs baseline: 1.0699x; 1.0699x over previous
//
#include <hip/hip_runtime.h>
#include <stdint.h>

// S6Layer on MI355X. B=8, L=4096, DM=256, DI=384, DS=8, CHUNK=32.
// R12 (this round), driven by R6 post-mortem: A-prefetch theory REFUTED
// (R9 per-kt loads == R10 window == 61us; VGPR=56 shows compiler sank the
// window at IR level). Real signals: FETCH 52MB vs 17MB ideal (A re-fetched
// 3x from HBM; 73MB write stream churns L3; same-x blocks scattered over
// XCDs) and nothing >30% busy (latency-bound block structure: DMA->barrier->
// 8-step K-loop->barrier->epilogue->barrier per 2-3k cy of work).
// Changes:
//  1. Persistent-B multi-M-tile blocks (MT=2): B panel staged ONCE per block,
//     then 2 M-tiles processed with ZERO interior barriers. Epilogue staging
//     moved to WAVE-PRIVATE LDS (sC, 32x72/wave) so the sB-reuse WAR barrier
//     pair disappears; same-wave DS ordering + one lgkmcnt(0) is enough.
//  2. XCD chunk swizzle (bijective, GX=128): XCD c owns x-chunk c, sweeps y
//     within it -> its 16 A-tiles (<=1.5MB) stay in its private 4MB L2 across
//     the 18/6/4 y-panel re-reads. A-loads HBM(~900cy) -> L2(~200cy).
// Grids (128,GY): 2304/768/512 blocks = 9/3/2 per CU, exactly balanced.
// R9 kept: A direct global->VGPR per kt; B swizzle folded to 2 bases+imm.
#define B_  8
#define L_  4096
#define DM  256
#define DI  384
#define DS  8
#define M_  (B_*L_)   // 32768 tokens

typedef float f32x4 __attribute__((ext_vector_type(4)));
typedef short s16x8 __attribute__((ext_vector_type(8)));

#define AS1(p) ((__attribute__((address_space(1))) void*)(p))
#define AS3(p) ((__attribute__((address_space(3))) void*)(p))

__device__ __forceinline__ unsigned short f2bf(float f) {
  union { float f; uint32_t u; } v; v.f = f;
  uint32_t r = v.u + 0x7FFFu + ((v.u >> 16) & 1u);   // RNE
  return (unsigned short)(r >> 16);
}
__device__ __forceinline__ float bf2f(unsigned short h) {
  union { uint32_t u; float f; } v; v.u = ((uint32_t)h) << 16;
  return v.f;
}
__device__ __forceinline__ float silu_f(float x) {
  return x * __builtin_amdgcn_rcpf(1.f + __expf(-x));
}

// ---------------- weight fp32 -> bf16 ----------------
__global__ __launch_bounds__(256) void cvt_kernel(
    const float* __restrict__ w0, const float* __restrict__ w1, const float* __restrict__ w2,
    unsigned short* __restrict__ o0, unsigned short* __restrict__ o1, unsigned short* __restrict__ o2) {
  int i = blockIdx.x * 256 + threadIdx.x;
  if (i < 3*DI*DM) o0[i] = f2bf(w0[i]);
  if (i < DI*DI)   o1[i] = f2bf(w1[i]);
  if (i < DM*DI)   o2[i] = f2bf(w2[i]);
}

// ---------------- layernorm: one wave per token ----------------
__global__ __launch_bounds__(256) void ln_kernel(
    const float* __restrict__ x, const float* __restrict__ gamma, const float* __restrict__ beta,
    unsigned short* __restrict__ xn) {
  int token = blockIdx.x * 4 + (threadIdx.x >> 6);
  int lane  = threadIdx.x & 63;
  const float4 v = *(const float4*)(x + (size_t)token*DM + lane*4);
  float s  = v.x + v.y + v.z + v.w;
  float ss = v.x*v.x + v.y*v.y + v.z*v.z + v.w*v.w;
  #pragma unroll
  for (int off = 32; off > 0; off >>= 1) {
    s  += __shfl_xor(s,  off, 64);
    ss += __shfl_xor(ss, off, 64);
  }
  float mean = s * (1.f/DM);
  float var  = ss * (1.f/DM) - mean*mean;
  float rstd = rsqrtf(var + 1e-5f);
  const float4 g = *(const float4*)(gamma + lane*4);
  const float4 b = *(const float4*)(beta  + lane*4);
  ushort4 o;
  o.x = f2bf((v.x - mean)*rstd*g.x + b.x);
  o.y = f2bf((v.y - mean)*rstd*g.y + b.y);
  o.z = f2bf((v.z - mean)*rstd*g.z + b.z);
  o.w = f2bf((v.w - mean)*rstd*g.w + b.w);
  *(ushort4*)(xn + (size_t)token*DM + lane*4) = o;
}

// ---------------- persistent-B MFMA GEMM, MT M-tiles per block -------------
// C[M,N] = A[M,K] @ Bw[N,K]^T. Block: 256 thr (4 waves); per block: ONE
// 64-col B panel (stationary in LDS) x MT tiles of 128 M-rows. Wave w owns
// rows w*32..w*32+31 of each tile x all 64 N.
// XCD swizzle (grid MUST be (128, GY)): q = by*128+bx; xcd=q&7 owns x-chunk
// [xcd*16, xcd*16+16), sweeping y -> A-tiles stay XCD-L2-resident.
// K-loop per kt: 2 global_load_dwordx4 (A) + 4 ds_read_b128 (B, swizzled,
// imm offsets off 2 per-lane bases) + 8 MFMA. One barrier per BLOCK.
template<int EPI, int KSTEPS, int MT>
__global__ __launch_bounds__(256, 3) void gemm_ws(
    const unsigned short* __restrict__ A,   // [M,K] bf16
    const unsigned short* __restrict__ Bw,  // [N,K] bf16
    const float* __restrict__ bias,         // [N]
    unsigned short* __restrict__ o_xp, unsigned short* __restrict__ o_z,
    unsigned short* __restrict__ o_dtin,    // EPI=1
    unsigned short* __restrict__ o_bf,      // EPI=2
    const float* __restrict__ resid, float* __restrict__ o_f)  // EPI=3
{
  constexpr int K    = KSTEPS * 32;
  constexpr int CPR  = K / 8;               // 16B chunks per B row
  __shared__ unsigned short sB[64*K];       // 48KB (K=384) / 32KB (K=256)
  __shared__ unsigned short sC[(EPI == 3) ? 2 : 4*32*72];  // wave-private C staging

  const int t    = threadIdx.x;
  const int lane = t & 63;
  const int w    = t >> 6;
  const int fr   = lane & 15;
  const int fq   = lane >> 4;
  const int wm   = w * 32;

  // ---- XCD chunk swizzle: bijective for grid (128, GY) ----
  const int q    = blockIdx.y * 128 + blockIdx.x;
  const int bx2  = (q & 7) * 16 + ((q >> 3) & 15);
  const int by2  = q >> 7;
  const int mbase0 = bx2 * (128 * MT);
  const int nbase  = by2 * 64;

  // ---- stage B panel (once per block): swizzled 16B chunks ----
  #pragma unroll
  for (int i = 0; i < (64*CPR)/256; ++i) {
    int c   = i*256 + t;
    int row = c / CPR;
    int j   = c - row*CPR;
    int jp  = (j & ~7) | ((j & 7) ^ (row & 7));
    __builtin_amdgcn_global_load_lds(AS1(Bw + (size_t)(nbase + row)*K + jp*8),
                                     AS3(sB + c*8), 16, 0, 0);
  }

  // ---- B LDS read bases: byte addr for (ni,kt) decomposes as
  //   fr*2K + ((fq^(fr&7)) ^ 4*(kt&1))*16  +  ni*32K + (kt>>1)*128
  const unsigned short* sBrE = sB + (size_t)fr*K + ( fq      ^ (fr & 7))*8;
  const unsigned short* sBrO = sB + (size_t)fr*K + ((fq | 4) ^ (fr & 7))*8;

  // per-thread bias values (cols ni*16+fr), loaded once
  float bvv[4];
  #pragma unroll
  for (int ni = 0; ni < 4; ++ni) bvv[ni] = bias[nbase + ni*16 + fr];

  unsigned short* sCw = sC + w*(32*72);     // wave-private staging (EPI 1/2)

  __syncthreads();   // B panel resident — the ONLY barrier in this kernel

  #pragma unroll
  for (int mt = 0; mt < MT; ++mt) {
    const int mbase = mbase0 + mt*128;
    const unsigned short* gA0 = A + (size_t)(mbase + wm + fr)*K + fq*8;
    const unsigned short* gA1 = gA0 + (size_t)16*K;

    f32x4 acc[2][4];
    #pragma unroll
    for (int mi = 0; mi < 2; ++mi)
      #pragma unroll
      for (int ni = 0; ni < 4; ++ni) acc[mi][ni] = (f32x4){0.f, 0.f, 0.f, 0.f};

    #pragma unroll
    for (int kt = 0; kt < KSTEPS; ++kt) {
      s16x8 a0 = *(const s16x8*)(gA0 + kt*32);
      s16x8 a1 = *(const s16x8*)(gA1 + kt*32);
      const unsigned short* bb = (kt & 1) ? sBrO : sBrE;
      s16x8 bfr[4];
      #pragma unroll
      for (int ni = 0; ni < 4; ++ni)
        bfr[ni] = *(const s16x8*)(bb + ni*16*K + (kt >> 1)*64);
      #pragma unroll
      for (int ni = 0; ni < 4; ++ni) {
        acc[0][ni] = __builtin_amdgcn_mfma_f32_16x16x32_bf16(a0, bfr[ni], acc[0][ni], 0, 0, 0);
        acc[1][ni] = __builtin_amdgcn_mfma_f32_16x16x32_bf16(a1, bfr[ni], acc[1][ni], 0, 0, 0);
      }
    }

    // ---- epilogue: C layout per 16x16 tile: col=fr, row=fq*4+r (m89) ----
    if constexpr (EPI == 3) {
      #pragma unroll
      for (int ni = 0; ni < 4; ++ni) {
        int gn = nbase + ni*16 + fr;
        #pragma unroll
        for (int mi = 0; mi < 2; ++mi) {
          int gm0 = mbase + wm + mi*16 + fq*4;
          #pragma unroll
          for (int r = 0; r < 4; ++r) {
            size_t gm = (size_t)(gm0 + r);
            o_f[gm*DM + gn] = acc[mi][ni][r] + bvv[ni] + resid[gm*DM + gn];
          }
        }
      }
    } else {
      // wave-private staging: no barriers (same-wave DS ops are in-order;
      // lgkmcnt(0) covers write->read visibility).
      const bool do_silu = (EPI == 1) && (by2 < 12);
      #pragma unroll
      for (int ni = 0; ni < 4; ++ni) {
        int cn = ni*16 + fr;
        #pragma unroll
        for (int mi = 0; mi < 2; ++mi) {
          int rm0 = mi*16 + fq*4;
          #pragma unroll
          for (int r = 0; r < 4; ++r) {
            float c = acc[mi][ni][r] + bvv[ni];
            if constexpr (EPI == 1) { if (do_silu) c = silu_f(c); }
            else                    { c = (c > 20.f) ? c : __logf(1.f + __expf(c)); }
            sCw[(rm0 + r)*72 + cn] = f2bf(c);
          }
        }
      }
      asm volatile("s_waitcnt lgkmcnt(0)" ::: "memory");
      unsigned short* dst;
      int colbase;
      if constexpr (EPI == 1) {
        dst = (by2 < 6) ? o_xp : (by2 < 12) ? o_z : o_dtin;
        colbase = (by2 % 6) * 64;
      } else {
        dst = o_bf; colbase = nbase;
      }
      const int rr = lane >> 3, cc = (lane & 7) * 8;
      #pragma unroll
      for (int it = 0; it < 4; ++it) {
        int row32 = rr + it*8;
        s16x8 v = *(const s16x8*)(sCw + row32*72 + cc);
        *(s16x8*)(dst + (size_t)(mbase + wm + row32)*DI + colbase + cc) = v;
      }
    }
  }
}

// ---------------- chunked selective scan ----------------
__global__ __launch_bounds__(384) void scan_kernel(
    const unsigned short* __restrict__ xp, const unsigned short* __restrict__ dt,
    const unsigned short* __restrict__ zb, const float* __restrict__ A_log,
    const float* __restrict__ D_vec, unsigned short* __restrict__ yz) {
  int g  = blockIdx.x;
  int di = threadIdx.x;
  size_t base = (size_t)g * 32 * DI + di;
  float a[DS];
  #pragma unroll
  for (int s = 0; s < DS; ++s) a[s] = -__expf(A_log[di*DS + s]);
  float Dv = D_vec[di];
  float h[DS] = {0.f,0.f,0.f,0.f,0.f,0.f,0.f,0.f};
  for (int tt = 0; tt < 32; ++tt) {
    size_t idx = base + (size_t)tt * DI;
    float xv  = bf2f(xp[idx]);
    float dtv = bf2f(dt[idx]);
    float y = 0.f;
    #pragma unroll
    for (int s = 0; s < DS; ++s) {
      h[s] = h[s] * __expf(dtv * a[s]) + xv;
      y += h[s];
    }
    float zv = bf2f(zb[idx]);
    yz[idx] = f2bf(y * zv + xv * Dv);
  }
}

extern "C" void kernel_launch(void* const* d_in, const int* in_sizes, int n_in,
                              void* d_out, int out_size, void* d_ws, size_t ws_size,
                              hipStream_t stream) {
  const float* x     = (const float*)d_in[0];
  const float* gamma = (const float*)d_in[1];
  const float* beta  = (const float*)d_in[2];
  const float* W_in  = (const float*)d_in[3];
  const float* b_in  = (const float*)d_in[4];
  const float* W_dt  = (const float*)d_in[5];
  const float* b_dt  = (const float*)d_in[6];
  const float* A_log = (const float*)d_in[7];
  const float* D_vec = (const float*)d_in[8];
  const float* W_out = (const float*)d_in[9];
  const float* b_out = (const float*)d_in[10];
  float* out = (float*)d_out;

  char* ws = (char*)d_ws;
  size_t off = 0;
  auto alloc = [&](size_t bytes) -> char* {
    char* p = ws + off; off += (bytes + 255) & ~(size_t)255; return p;
  };
  unsigned short* xn    = (unsigned short*)alloc((size_t)M_*DM*2);
  unsigned short* xpb   = (unsigned short*)alloc((size_t)M_*DI*2);
  unsigned short* zb    = (unsigned short*)alloc((size_t)M_*DI*2);
  unsigned short* dtin  = (unsigned short*)alloc((size_t)M_*DI*2);
  unsigned short* dtb   = (unsigned short*)alloc((size_t)M_*DI*2);
  unsigned short* yzb   = dtin;   // dtin dead after GEMM2 -> reuse for yz
  unsigned short* winb  = (unsigned short*)alloc((size_t)3*DI*DM*2);
  unsigned short* wdtb  = (unsigned short*)alloc((size_t)DI*DI*2);
  unsigned short* woutb = (unsigned short*)alloc((size_t)DM*DI*2);

  cvt_kernel<<<dim3((3*DI*DM + 255)/256), 256, 0, stream>>>(W_in, W_dt, W_out, winb, wdtb, woutb);
  ln_kernel<<<dim3(M_/4), 256, 0, stream>>>(x, gamma, beta, xn);
  // GEMM1: xn[M,256] @ W_in[1152,256]^T -> silu(xp), silu(z), dtin
  gemm_ws<1, 8, 2><<<dim3(128, (3*DI)/64), 256, 0, stream>>>(
      xn, winb, b_in, xpb, zb, dtin, nullptr, nullptr, nullptr);
  // GEMM2: dtin[M,384] @ W_dt[384,384]^T ; softplus -> dt
  gemm_ws<2, 12, 2><<<dim3(128, DI/64), 256, 0, stream>>>(
      dtin, wdtb, b_dt, nullptr, nullptr, nullptr, dtb, nullptr, nullptr);
  // scan -> yz = y*z + xp*D
  scan_kernel<<<dim3(M_/32), DI, 0, stream>>>(xpb, dtb, zb, A_log, D_vec, yzb);
  // GEMM3: yz[M,384] @ W_out[256,384]^T + b_out + residual -> out (fp32)
  gemm_ws<3, 12, 2><<<dim3(128, DM/64), 256, 0, stream>>>(
      yzb, woutb, b_out, nullptr, nullptr, nullptr, nullptr, x, out);
}